// Round 7
// baseline (2457.611 us; speedup 1.0000x reference)
//
#include <hip/hip_runtime.h>
#include <math.h>

#define TS 12
#define HEADS 8
#define DH 8
#define DD 64
#define BB 16
#define NN 325
#define BN (BB*NN)               // 5200
#define TOT (TS*BN*DD)           // 3,993,600
#define ROWS_FC (BB*TS*NN)       // 62,400
#define NPAD 336                 // 21 tiles of 16
#define NT 21
#define CHUNK 26                 // pairs per chunk (78 = 3*26)
constexpr float EPS_ = 1e-5f;
constexpr float SCALE_ = 0.35355339059327373f; // 1/sqrt(8)

typedef _Float16 f16x4 __attribute__((ext_vector_type(4)));
typedef float    f32x4 __attribute__((ext_vector_type(4)));

// ---------------- K1: QKV GEMM (16 rows/block) ----------------
__global__ __launch_bounds__(256) void qkv_gemm(
    const float* __restrict__ X, const float* __restrict__ STE,
    const float* __restrict__ Wqkv, const float* __restrict__ bqkv,
    float* __restrict__ Y)
{
    __shared__ float Wl[128*64];
    int t = blockIdx.y;
    int tid = threadIdx.x;
    for (int i = tid; i < 2048; i += 256)
        ((float4*)Wl)[i] = ((const float4*)Wqkv)[i];
    __syncthreads();
    int c = tid & 63, rl = tid >> 6;
    #pragma unroll
    for (int rr = 0; rr < 4; ++rr) {
        int r = blockIdx.x * 16 + rr * 4 + rl;
        int b = r / NN, n = r % NN;
        const float4* xr = (const float4*)(X   + (((size_t)b*TS + t)*NN + n)*DD);
        const float4* sr = (const float4*)(STE + (((size_t)b*TS + t)*NN + n)*DD);
        float acc = bqkv[c];
        #pragma unroll
        for (int k4 = 0; k4 < 16; ++k4) {
            float4 xv = xr[k4];
            acc += xv.x*Wl[(4*k4+0)*64+c] + xv.y*Wl[(4*k4+1)*64+c]
                 + xv.z*Wl[(4*k4+2)*64+c] + xv.w*Wl[(4*k4+3)*64+c];
        }
        #pragma unroll
        for (int k4 = 0; k4 < 16; ++k4) {
            float4 sv = sr[k4];
            acc += sv.x*Wl[(64+4*k4+0)*64+c] + sv.y*Wl[(64+4*k4+1)*64+c]
                 + sv.z*Wl[(64+4*k4+2)*64+c] + sv.w*Wl[(64+4*k4+3)*64+c];
        }
        Y[((size_t)t*BN + r)*64 + c] = acc;
    }
}

// ---------------- K2: column reduce (sum, sumsq) over [t][R][64] ----------------
__global__ __launch_bounds__(256) void col_reduce(
    const float* __restrict__ src, float* __restrict__ osum, float* __restrict__ osumsq,
    int R, int chunkrows)
{
    __shared__ float red[256];
    int t = blockIdx.y;
    int tid = threadIdx.x;
    int c = tid & 63, rl = tid >> 6;
    int r0 = blockIdx.x * chunkrows;
    int r1 = r0 + chunkrows;
    float s = 0.f, s2 = 0.f;
    for (int r = r0 + rl; r < r1; r += 4) {
        float v = src[((size_t)t*R + r)*64 + c];
        s += v; s2 += v*v;
    }
    red[tid] = s; __syncthreads();
    if (tid < 64) atomicAdd(&osum[t*64 + tid], red[tid] + red[tid+64] + red[tid+128] + red[tid+192]);
    __syncthreads();
    red[tid] = s2; __syncthreads();
    if (tid < 64) atomicAdd(&osumsq[t*64 + tid], red[tid] + red[tid+64] + red[tid+128] + red[tid+192]);
}

// ---------------- K3: finalize QKV BN stats ----------------
__global__ void qkv_stats(const float* __restrict__ qsum, const float* __restrict__ qsumsq,
                          const float* __restrict__ g, const float* __restrict__ be,
                          float* __restrict__ qsc, float* __restrict__ qsh)
{
    int i = blockIdx.x * blockDim.x + threadIdx.x;
    if (i >= TS*64) return;
    int c = i & 63;
    float mean = qsum[i] * (1.0f / BN);
    float var  = qsumsq[i] * (1.0f / BN) - mean*mean;
    float sc = g[c] * rsqrtf(var + EPS_);
    qsc[i] = sc;
    qsh[i] = be[c] - mean * sc;
}

// ---------------- K4: BN+ReLU + relayout to f16 [t][b][h][n][8] ----------------
__global__ __launch_bounds__(256) void bn_relayout_h(
    const float* __restrict__ Y, const float* __restrict__ qsc, const float* __restrict__ qsh,
    _Float16* __restrict__ qkvh)
{
    size_t idx = (size_t)blockIdx.x * 256 + threadIdx.x;
    if (idx >= TOT) return;
    int c = (int)(idx & 63);
    size_t tr = idx >> 6;
    int t = (int)(tr / BN);
    int r = (int)(tr % BN);
    float v = fmaxf(Y[idx] * qsc[t*64 + c] + qsh[t*64 + c], 0.0f);
    int b = r / NN, n = r % NN, h = c >> 3, d = c & 7;
    qkvh[((((size_t)t*BB + b)*HEADS + h)*NN + n)*DH + d] = (_Float16)v;
}

// ---------------- K5: MFMA attention, plain stores to pair-chunked ocat ----------------
// Block = (pl, b, h), pair p = p0+pl. S^T = K·Q^T via mfma_f32_16x16x16_f16;
// C-frag == B-frag layout for O^T = V^T·P^T (zero cross-lane movement).
// Two-pass softmax keeps P in [0,1] for f16. O strip stored as float4 to
// ocat[pl][b][n][h*8+d] — NO atomics.
__global__ __launch_bounds__(256, 8) void attn_ocat(
    const _Float16* __restrict__ qkvh, float* __restrict__ ocat, int p0)
{
    int pl = blockIdx.x, b = blockIdx.y, h = blockIdx.z;
    int p = p0 + pl;
    int s = 0, base = 0;
    while (base + s + 1 <= p) { base += s + 1; ++s; }
    int j = p - base;

    __shared__ _Float16 Kl[NPAD*8];          // [m][k], rows m>=325 zero
    __shared__ _Float16 VT[16][NPAD+8];      // [d][m], d>=8 & m>=325 zero

    int tid  = threadIdx.x;
    int lane = tid & 63, wv = tid >> 6;
    int lq = lane >> 4, lr = lane & 15;

    for (int i = tid; i < (NPAD*8)/2; i += 256) ((unsigned*)Kl)[i] = 0u;
    for (int i = tid; i < (16*(NPAD+8))/2; i += 256) ((unsigned*)(&VT[0][0]))[i] = 0u;
    __syncthreads();
    const _Float16* kvsrc = qkvh + (((size_t)j*BB + b)*HEADS + h)*(NN*DH);
    for (int i = tid; i < (NN*DH)/2; i += 256) ((unsigned*)Kl)[i] = ((const unsigned*)kvsrc)[i];
    for (int i = tid; i < NN*DH; i += 256) { int m = i >> 3, d = i & 7; VT[d][m] = kvsrc[i]; }
    __syncthreads();

    const _Float16* qh = qkvh + (((size_t)s*BB + b)*HEADS + h)*(NN*DH);

    for (int st = wv; st < NT; st += 4) {
        int n0 = st * 16;
        f16x4 qf = {0,0,0,0};
        int nq = n0 + lr;
        if (lq < 2 && nq < NN) qf = *(const f16x4*)(qh + nq*DH + lq*4);
        qf *= (_Float16)SCALE_;

        // pass 1: row max (pad rows give 0; true max >= 0 since Q,K >= 0)
        float mx = 0.f;
        for (int mt = 0; mt < NT; ++mt) {
            f16x4 kf = {0,0,0,0};
            if (lq < 2) kf = *(const f16x4*)(&Kl[(mt*16 + lr)*8 + lq*4]);
            f32x4 sA = __builtin_amdgcn_mfma_f32_16x16x16f16(kf, qf, (f32x4){0.f,0.f,0.f,0.f}, 0, 0, 0);
            mx = fmaxf(mx, fmaxf(fmaxf(sA[0], sA[1]), fmaxf(sA[2], sA[3])));
        }
        mx = fmaxf(mx, __shfl_xor(mx, 16));
        mx = fmaxf(mx, __shfl_xor(mx, 32));

        // pass 2: exp(S-mx), den, O^T = V^T · P^T
        f32x4 ot = {0.f, 0.f, 0.f, 0.f};
        float den = 0.f;
        for (int mt = 0; mt < NT; ++mt) {
            f16x4 kf = {0,0,0,0};
            if (lq < 2) kf = *(const f16x4*)(&Kl[(mt*16 + lr)*8 + lq*4]);
            f32x4 sA = __builtin_amdgcn_mfma_f32_16x16x16f16(kf, qf, (f32x4){0.f,0.f,0.f,0.f}, 0, 0, 0);
            f16x4 pf;
            #pragma unroll
            for (int r = 0; r < 4; ++r) {
                float e = __expf(sA[r] - mx);
                if (mt*16 + lq*4 + r >= NN) e = 0.f;   // mask pad rows
                den += e;
                pf[r] = (_Float16)e;
            }
            f16x4 vf = *(const f16x4*)(&VT[lr][mt*16 + lq*4]);
            ot = __builtin_amdgcn_mfma_f32_16x16x16f16(vf, pf, ot, 0, 0, 0);
        }
        den += __shfl_xor(den, 16);
        den += __shfl_xor(den, 32);
        float inv = 1.0f / den;

        // store O strip: lane (lq<2, lr) holds O^T[d=4lq+r][n=n0+lr]
        if (lq < 2 && nq < NN) {
            float4 o4 = make_float4(ot[0]*inv, ot[1]*inv, ot[2]*inv, ot[3]*inv);
            *(float4*)(ocat + (((size_t)(pl*BB + b))*NN + nq)*64 + h*8 + lq*4) = o4;
        }
    }
}

// ---------------- K6: per-step linear over concat chunk, accumulate into Xo ----------------
// Block = (rowtile, s). For chunk [p0,p1): j in [j0,j1).
// SEED FIX: seed with lin_b iff this chunk contains j=0 for step s
// (p0 <= base), NOT p0==0 — steps whose base falls in a later chunk were
// previously seeded from uninitialized d_out (poison on replay).
__global__ __launch_bounds__(256) void lin_chunk(
    const float* __restrict__ ocat, const float* __restrict__ lin_w,
    const float* __restrict__ lin_b, float* Xo, int p0, int p1)
{
    int s = blockIdx.y;
    int base = s*(s+1)/2;
    int j0 = p0 - base; if (j0 < 0) j0 = 0;
    int j1 = s + 1; if (j1 > p1 - base) j1 = p1 - base;
    if (j1 <= j0) return;
    bool seed = (p0 <= base);   // first chunk containing this step's j=0

    __shared__ float Wl[64*64];
    int tid = threadIdx.x;
    int c = tid & 63, rl = tid >> 6;

    float acc[4];
    size_t xoff[4], bnoff[4];
    #pragma unroll
    for (int rr = 0; rr < 4; ++rr) {
        int r = blockIdx.x*16 + rr*4 + rl;
        int b = r / NN, n = r % NN;
        xoff[rr]  = (((size_t)b*TS + s)*NN + n)*64 + c;
        bnoff[rr] = ((size_t)b*NN + n)*64;
        acc[rr] = seed ? lin_b[s*64 + c] : Xo[xoff[rr]];
    }

    for (int jj = j0; jj < j1; ++jj) {
        __syncthreads();
        const float4* wsrc = (const float4*)(lin_w + ((size_t)s*768 + jj*64)*64);
        for (int i = tid; i < 1024; i += 256) ((float4*)Wl)[i] = wsrc[i];
        __syncthreads();
        size_t plo = (size_t)(base + jj - p0) * (BB*NN) * 64;
        #pragma unroll
        for (int rr = 0; rr < 4; ++rr) {
            const float4* orow = (const float4*)(ocat + plo + bnoff[rr]);
            #pragma unroll
            for (int k4 = 0; k4 < 16; ++k4) {
                float4 ov = orow[k4];
                acc[rr] += ov.x*Wl[(4*k4+0)*64+c] + ov.y*Wl[(4*k4+1)*64+c]
                         + ov.z*Wl[(4*k4+2)*64+c] + ov.w*Wl[(4*k4+3)*64+c];
            }
        }
    }
    #pragma unroll
    for (int rr = 0; rr < 4; ++rr) Xo[xoff[rr]] = acc[rr];
}

// ---------------- K7: fc GEMM, IN PLACE on d_out (row-local, race-free) ----------------
__global__ __launch_bounds__(256) void fc_gemm(
    const float* Xo, const float* __restrict__ Wfc, const float* __restrict__ bfc,
    float* Yout)
{
    __shared__ float Wl[64*64];
    int tid = threadIdx.x;
    for (int i = tid; i < 1024; i += 256)
        ((float4*)Wl)[i] = ((const float4*)Wfc)[i];
    __syncthreads();
    int c = tid & 63, rl = tid >> 6;
    #pragma unroll
    for (int rr = 0; rr < 4; ++rr) {
        size_t r = (size_t)blockIdx.x * 16 + rr * 4 + rl;
        const float4* xr = (const float4*)(Xo + r * 64);
        float acc = bfc[c];
        #pragma unroll
        for (int k4 = 0; k4 < 16; ++k4) {
            float4 xv = xr[k4];
            acc += xv.x*Wl[(4*k4+0)*64+c] + xv.y*Wl[(4*k4+1)*64+c]
                 + xv.z*Wl[(4*k4+2)*64+c] + xv.w*Wl[(4*k4+3)*64+c];
        }
        Yout[r*64 + c] = acc;
    }
}

// ---------------- K8: finalize fc BN stats ----------------
__global__ void fc_stats(const float* __restrict__ fsum, const float* __restrict__ fsumsq,
                         const float* __restrict__ g, const float* __restrict__ be,
                         float* __restrict__ fsc, float* __restrict__ fsh)
{
    int c = threadIdx.x;
    if (c >= 64) return;
    float mean = fsum[c] * (1.0f / ROWS_FC);
    float var  = fsumsq[c] * (1.0f / ROWS_FC) - mean*mean;
    float sc = g[c] * rsqrtf(var + EPS_);
    fsc[c] = sc;
    fsh[c] = be[c] - mean * sc;
}

// ---------------- K9: final BN+ReLU in place on d_out ----------------
__global__ __launch_bounds__(256) void bn_out(
    float* __restrict__ out, const float* __restrict__ fsc, const float* __restrict__ fsh)
{
    size_t idx = (size_t)blockIdx.x * 256 + threadIdx.x;
    if (idx >= TOT) return;
    int c = (int)(idx & 63);
    out[idx] = fmaxf(out[idx] * fsc[c] + fsh[c], 0.0f);
}

extern "C" void kernel_launch(void* const* d_in, const int* in_sizes, int n_in,
                              void* d_out, int out_size, void* d_ws, size_t ws_size,
                              hipStream_t stream)
{
    const float* X     = (const float*)d_in[0];
    const float* STE   = (const float*)d_in[1];
    const float* Wqkv  = (const float*)d_in[2];
    const float* bqkv  = (const float*)d_in[3];
    const float* gqkv  = (const float*)d_in[4];
    const float* beqkv = (const float*)d_in[5];
    const float* lin_w = (const float*)d_in[6];
    const float* lin_b = (const float*)d_in[7];
    const float* Wfc   = (const float*)d_in[8];
    const float* bfc   = (const float*)d_in[9];
    const float* gfc   = (const float*)d_in[10];
    const float* befc  = (const float*)d_in[11];

    // ws layout (f32 units): [qkvh: TOT/2][stats: 4096][ocat: CHUNK*BB*NN*64]
    // Y (TOT) lives inside the ocat region (dead before attn writes ocat).
    float* ws    = (float*)d_ws;
    _Float16* qkvh = (_Float16*)ws;
    float* st    = ws + (size_t)TOT/2;
    float* ocat  = st + 4096;
    float* Y     = ocat;
    float* Xo    = (float*)d_out;          // Xo lives in d_out; fc runs in place

    float* qsum   = st;            // 768
    float* qsumsq = st + 768;      // 768
    float* fsum   = st + 1536;     // 64
    float* fsumsq = st + 1600;     // 64  -> first 1664 floats zeroed each call
    float* qsc    = st + 1664;     // 768
    float* qsh    = st + 2432;     // 768
    float* fsc    = st + 3200;     // 64
    float* fsh    = st + 3264;     // 64

    hipMemsetAsync(st, 0, 1664 * sizeof(float), stream);

    qkv_gemm<<<dim3(BN/16, TS), 256, 0, stream>>>(X, STE, Wqkv, bqkv, Y);
    col_reduce<<<dim3(8, TS), 256, 0, stream>>>(Y, qsum, qsumsq, BN, BN/8);
    qkv_stats<<<3, 256, 0, stream>>>(qsum, qsumsq, gqkv, beqkv, qsc, qsh);
    bn_relayout_h<<<TOT/256, 256, 0, stream>>>(Y, qsc, qsh, qkvh);

    for (int ch = 0; ch < 3; ++ch) {
        int p0 = ch * CHUNK, p1 = p0 + CHUNK;
        attn_ocat<<<dim3(CHUNK, BB, HEADS), 256, 0, stream>>>(qkvh, ocat, p0);
        lin_chunk<<<dim3(BN/16, TS), 256, 0, stream>>>(ocat, lin_w, lin_b, Xo, p0, p1);
    }

    fc_gemm<<<ROWS_FC/16, 256, 0, stream>>>(Xo, Wfc, bfc, (float*)d_out);
    col_reduce<<<dim3(96, 1), 256, 0, stream>>>((float*)d_out, fsum, fsumsq, ROWS_FC, ROWS_FC/96);
    fc_stats<<<1, 64, 0, stream>>>(fsum, fsumsq, gfc, befc, fsc, fsh);
    bn_out<<<TOT/256, 256, 0, stream>>>((float*)d_out, fsc, fsh);
}

// Round 8
// 2329.266 us; speedup vs baseline: 1.0551x; 1.0551x over previous
//
#include <hip/hip_runtime.h>
#include <math.h>

#define TS 12
#define HEADS 8
#define DH 8
#define DD 64
#define BB 16
#define NN 325
#define BN (BB*NN)               // 5200
#define TOT (TS*BN*DD)           // 3,993,600
#define ROWS_FC (BB*TS*NN)       // 62,400
#define NPAD 336                 // 21 tiles of 16
#define NT 21
#define CHUNK 26                 // pairs per chunk (78 = 3*26)
constexpr float EPS_ = 1e-5f;
constexpr float SCALE_ = 0.35355339059327373f; // 1/sqrt(8)

typedef _Float16 f16x4 __attribute__((ext_vector_type(4)));
typedef float    f32x4 __attribute__((ext_vector_type(4)));

// ---------------- K1: QKV GEMM (16 rows/block) ----------------
__global__ __launch_bounds__(256) void qkv_gemm(
    const float* __restrict__ X, const float* __restrict__ STE,
    const float* __restrict__ Wqkv, const float* __restrict__ bqkv,
    float* __restrict__ Y)
{
    __shared__ float Wl[128*64];
    int t = blockIdx.y;
    int tid = threadIdx.x;
    for (int i = tid; i < 2048; i += 256)
        ((float4*)Wl)[i] = ((const float4*)Wqkv)[i];
    __syncthreads();
    int c = tid & 63, rl = tid >> 6;
    #pragma unroll
    for (int rr = 0; rr < 4; ++rr) {
        int r = blockIdx.x * 16 + rr * 4 + rl;
        int b = r / NN, n = r % NN;
        const float4* xr = (const float4*)(X   + (((size_t)b*TS + t)*NN + n)*DD);
        const float4* sr = (const float4*)(STE + (((size_t)b*TS + t)*NN + n)*DD);
        float acc = bqkv[c];
        #pragma unroll
        for (int k4 = 0; k4 < 16; ++k4) {
            float4 xv = xr[k4];
            acc += xv.x*Wl[(4*k4+0)*64+c] + xv.y*Wl[(4*k4+1)*64+c]
                 + xv.z*Wl[(4*k4+2)*64+c] + xv.w*Wl[(4*k4+3)*64+c];
        }
        #pragma unroll
        for (int k4 = 0; k4 < 16; ++k4) {
            float4 sv = sr[k4];
            acc += sv.x*Wl[(64+4*k4+0)*64+c] + sv.y*Wl[(64+4*k4+1)*64+c]
                 + sv.z*Wl[(64+4*k4+2)*64+c] + sv.w*Wl[(64+4*k4+3)*64+c];
        }
        Y[((size_t)t*BN + r)*64 + c] = acc;
    }
}

// ---------------- K2: column reduce (sum, sumsq) over [t][R][64] ----------------
__global__ __launch_bounds__(256) void col_reduce(
    const float* __restrict__ src, float* __restrict__ osum, float* __restrict__ osumsq,
    int R, int chunkrows)
{
    __shared__ float red[256];
    int t = blockIdx.y;
    int tid = threadIdx.x;
    int c = tid & 63, rl = tid >> 6;
    int r0 = blockIdx.x * chunkrows;
    int r1 = r0 + chunkrows;
    float s = 0.f, s2 = 0.f;
    for (int r = r0 + rl; r < r1; r += 4) {
        float v = src[((size_t)t*R + r)*64 + c];
        s += v; s2 += v*v;
    }
    red[tid] = s; __syncthreads();
    if (tid < 64) atomicAdd(&osum[t*64 + tid], red[tid] + red[tid+64] + red[tid+128] + red[tid+192]);
    __syncthreads();
    red[tid] = s2; __syncthreads();
    if (tid < 64) atomicAdd(&osumsq[t*64 + tid], red[tid] + red[tid+64] + red[tid+128] + red[tid+192]);
}

// ---------------- K3: finalize QKV BN stats ----------------
__global__ void qkv_stats(const float* __restrict__ qsum, const float* __restrict__ qsumsq,
                          const float* __restrict__ g, const float* __restrict__ be,
                          float* __restrict__ qsc, float* __restrict__ qsh)
{
    int i = blockIdx.x * blockDim.x + threadIdx.x;
    if (i >= TS*64) return;
    int c = i & 63;
    float mean = qsum[i] * (1.0f / BN);
    float var  = qsumsq[i] * (1.0f / BN) - mean*mean;
    float sc = g[c] * rsqrtf(var + EPS_);
    qsc[i] = sc;
    qsh[i] = be[c] - mean * sc;
}

// ---------------- K4: BN+ReLU + relayout to f16 [t][b][h][n][8] ----------------
__global__ __launch_bounds__(256) void bn_relayout_h(
    const float* __restrict__ Y, const float* __restrict__ qsc, const float* __restrict__ qsh,
    _Float16* __restrict__ qkvh)
{
    size_t idx = (size_t)blockIdx.x * 256 + threadIdx.x;
    if (idx >= TOT) return;
    int c = (int)(idx & 63);
    size_t tr = idx >> 6;
    int t = (int)(tr / BN);
    int r = (int)(tr % BN);
    float v = fmaxf(Y[idx] * qsc[t*64 + c] + qsh[t*64 + c], 0.0f);
    int b = r / NN, n = r % NN, h = c >> 3, d = c & 7;
    qkvh[((((size_t)t*BB + b)*HEADS + h)*NN + n)*DH + d] = (_Float16)v;
}

// ---------------- K5: MFMA attention, block-exclusive contiguous ocat ----------------
// Block = (pl, b, h), pair p = p0+pl. S^T = K·Q^T via mfma_f32_16x16x16_f16;
// C-frag == B-frag layout for O^T = V^T·P^T (zero cross-lane movement).
// Two-pass softmax keeps P in [0,1] for f16.
// LAYOUT FIX vs R7: ocat is [pl][b][h][n][8] — each block owns a contiguous
// 10.4 KB region, no cache line shared between blocks (R7's h-interleaved rows
// caused 2.6 GB/chunk of RMW false-sharing traffic through HBM).
__global__ __launch_bounds__(256, 8) void attn_ocat(
    const _Float16* __restrict__ qkvh, float* __restrict__ ocat, int p0)
{
    int pl = blockIdx.x, b = blockIdx.y, h = blockIdx.z;
    int p = p0 + pl;
    int s = 0, base = 0;
    while (base + s + 1 <= p) { base += s + 1; ++s; }
    int j = p - base;

    __shared__ _Float16 Kl[NPAD*8];          // [m][k], rows m>=325 zero
    __shared__ _Float16 VT[16][NPAD+8];      // [d][m], d>=8 & m>=325 zero

    int tid  = threadIdx.x;
    int lane = tid & 63, wv = tid >> 6;
    int lq = lane >> 4, lr = lane & 15;

    for (int i = tid; i < (NPAD*8)/2; i += 256) ((unsigned*)Kl)[i] = 0u;
    for (int i = tid; i < (16*(NPAD+8))/2; i += 256) ((unsigned*)(&VT[0][0]))[i] = 0u;
    __syncthreads();
    const _Float16* kvsrc = qkvh + (((size_t)j*BB + b)*HEADS + h)*(NN*DH);
    for (int i = tid; i < (NN*DH)/2; i += 256) ((unsigned*)Kl)[i] = ((const unsigned*)kvsrc)[i];
    for (int i = tid; i < NN*DH; i += 256) { int m = i >> 3, d = i & 7; VT[d][m] = kvsrc[i]; }
    __syncthreads();

    const _Float16* qh = qkvh + (((size_t)s*BB + b)*HEADS + h)*(NN*DH);
    float* obase = ocat + (((size_t)(pl*BB + b)*HEADS + h)*NN)*8;

    for (int st = wv; st < NT; st += 4) {
        int n0 = st * 16;
        f16x4 qf = {0,0,0,0};
        int nq = n0 + lr;
        if (lq < 2 && nq < NN) qf = *(const f16x4*)(qh + nq*DH + lq*4);
        qf *= (_Float16)SCALE_;

        // pass 1: row max (pad rows give 0; true max >= 0 since Q,K >= 0)
        float mx = 0.f;
        for (int mt = 0; mt < NT; ++mt) {
            f16x4 kf = {0,0,0,0};
            if (lq < 2) kf = *(const f16x4*)(&Kl[(mt*16 + lr)*8 + lq*4]);
            f32x4 sA = __builtin_amdgcn_mfma_f32_16x16x16f16(kf, qf, (f32x4){0.f,0.f,0.f,0.f}, 0, 0, 0);
            mx = fmaxf(mx, fmaxf(fmaxf(sA[0], sA[1]), fmaxf(sA[2], sA[3])));
        }
        mx = fmaxf(mx, __shfl_xor(mx, 16));
        mx = fmaxf(mx, __shfl_xor(mx, 32));

        // pass 2: exp(S-mx), den, O^T = V^T · P^T
        f32x4 ot = {0.f, 0.f, 0.f, 0.f};
        float den = 0.f;
        for (int mt = 0; mt < NT; ++mt) {
            f16x4 kf = {0,0,0,0};
            if (lq < 2) kf = *(const f16x4*)(&Kl[(mt*16 + lr)*8 + lq*4]);
            f32x4 sA = __builtin_amdgcn_mfma_f32_16x16x16f16(kf, qf, (f32x4){0.f,0.f,0.f,0.f}, 0, 0, 0);
            f16x4 pf;
            #pragma unroll
            for (int r = 0; r < 4; ++r) {
                float e = __expf(sA[r] - mx);
                if (mt*16 + lq*4 + r >= NN) e = 0.f;   // mask pad rows
                den += e;
                pf[r] = (_Float16)e;
            }
            f16x4 vf = *(const f16x4*)(&VT[lr][mt*16 + lq*4]);
            ot = __builtin_amdgcn_mfma_f32_16x16x16f16(vf, pf, ot, 0, 0, 0);
        }
        den += __shfl_xor(den, 16);
        den += __shfl_xor(den, 32);
        float inv = 1.0f / den;

        // store O strip contiguously: lane (lq<2, lr) -> obase[nq*8 + lq*4]
        if (lq < 2 && nq < NN) {
            float4 o4 = make_float4(ot[0]*inv, ot[1]*inv, ot[2]*inv, ot[3]*inv);
            *(float4*)(obase + (size_t)nq*8 + lq*4) = o4;
        }
    }
}

// ---------------- K6: per-step linear over concat chunk, accumulate into Xo ----------------
// Block = (rowtile, s). ocat layout [pl][b][h][n][8]. Seed with lin_b iff this
// chunk contains j=0 for step s (p0 <= base); later chunks RMW Xo.
__global__ __launch_bounds__(256) void lin_chunk(
    const float* __restrict__ ocat, const float* __restrict__ lin_w,
    const float* __restrict__ lin_b, float* Xo, int p0, int p1)
{
    int s = blockIdx.y;
    int base = s*(s+1)/2;
    int j0 = p0 - base; if (j0 < 0) j0 = 0;
    int j1 = s + 1; if (j1 > p1 - base) j1 = p1 - base;
    if (j1 <= j0) return;
    bool seed = (p0 <= base);   // first chunk containing this step's j=0

    __shared__ float Wl[64*64];
    int tid = threadIdx.x;
    int c = tid & 63, rl = tid >> 6;

    float acc[4];
    size_t xoff[4];
    int bb[4], nn_[4];
    #pragma unroll
    for (int rr = 0; rr < 4; ++rr) {
        int r = blockIdx.x*16 + rr*4 + rl;
        int b = r / NN, n = r % NN;
        bb[rr] = b; nn_[rr] = n;
        xoff[rr] = (((size_t)b*TS + s)*NN + n)*64 + c;
        acc[rr] = seed ? lin_b[s*64 + c] : Xo[xoff[rr]];
    }

    for (int jj = j0; jj < j1; ++jj) {
        __syncthreads();
        const float4* wsrc = (const float4*)(lin_w + ((size_t)s*768 + jj*64)*64);
        for (int i = tid; i < 1024; i += 256) ((float4*)Wl)[i] = wsrc[i];
        __syncthreads();
        int pl = base + jj - p0;
        #pragma unroll
        for (int rr = 0; rr < 4; ++rr) {
            const float* op0 = ocat + (((size_t)(pl*BB + bb[rr])*HEADS)*NN + nn_[rr])*8;
            #pragma unroll
            for (int h = 0; h < 8; ++h) {
                const float4* op = (const float4*)(op0 + (size_t)h*NN*8);
                float4 oa = op[0], ob = op[1];
                acc[rr] += oa.x*Wl[(h*8+0)*64+c] + oa.y*Wl[(h*8+1)*64+c]
                         + oa.z*Wl[(h*8+2)*64+c] + oa.w*Wl[(h*8+3)*64+c]
                         + ob.x*Wl[(h*8+4)*64+c] + ob.y*Wl[(h*8+5)*64+c]
                         + ob.z*Wl[(h*8+6)*64+c] + ob.w*Wl[(h*8+7)*64+c];
            }
        }
    }
    #pragma unroll
    for (int rr = 0; rr < 4; ++rr) Xo[xoff[rr]] = acc[rr];
}

// ---------------- K7: fc GEMM, IN PLACE on d_out (row-local, race-free) ----------------
__global__ __launch_bounds__(256) void fc_gemm(
    const float* Xo, const float* __restrict__ Wfc, const float* __restrict__ bfc,
    float* Yout)
{
    __shared__ float Wl[64*64];
    int tid = threadIdx.x;
    for (int i = tid; i < 1024; i += 256)
        ((float4*)Wl)[i] = ((const float4*)Wfc)[i];
    __syncthreads();
    int c = tid & 63, rl = tid >> 6;
    #pragma unroll
    for (int rr = 0; rr < 4; ++rr) {
        size_t r = (size_t)blockIdx.x * 16 + rr * 4 + rl;
        const float4* xr = (const float4*)(Xo + r * 64);
        float acc = bfc[c];
        #pragma unroll
        for (int k4 = 0; k4 < 16; ++k4) {
            float4 xv = xr[k4];
            acc += xv.x*Wl[(4*k4+0)*64+c] + xv.y*Wl[(4*k4+1)*64+c]
                 + xv.z*Wl[(4*k4+2)*64+c] + xv.w*Wl[(4*k4+3)*64+c];
        }
        Yout[r*64 + c] = acc;
    }
}

// ---------------- K8: finalize fc BN stats ----------------
__global__ void fc_stats(const float* __restrict__ fsum, const float* __restrict__ fsumsq,
                         const float* __restrict__ g, const float* __restrict__ be,
                         float* __restrict__ fsc, float* __restrict__ fsh)
{
    int c = threadIdx.x;
    if (c >= 64) return;
    float mean = fsum[c] * (1.0f / ROWS_FC);
    float var  = fsumsq[c] * (1.0f / ROWS_FC) - mean*mean;
    float sc = g[c] * rsqrtf(var + EPS_);
    fsc[c] = sc;
    fsh[c] = be[c] - mean * sc;
}

// ---------------- K9: final BN+ReLU in place on d_out ----------------
__global__ __launch_bounds__(256) void bn_out(
    float* __restrict__ out, const float* __restrict__ fsc, const float* __restrict__ fsh)
{
    size_t idx = (size_t)blockIdx.x * 256 + threadIdx.x;
    if (idx >= TOT) return;
    int c = (int)(idx & 63);
    out[idx] = fmaxf(out[idx] * fsc[c] + fsh[c], 0.0f);
}

extern "C" void kernel_launch(void* const* d_in, const int* in_sizes, int n_in,
                              void* d_out, int out_size, void* d_ws, size_t ws_size,
                              hipStream_t stream)
{
    const float* X     = (const float*)d_in[0];
    const float* STE   = (const float*)d_in[1];
    const float* Wqkv  = (const float*)d_in[2];
    const float* bqkv  = (const float*)d_in[3];
    const float* gqkv  = (const float*)d_in[4];
    const float* beqkv = (const float*)d_in[5];
    const float* lin_w = (const float*)d_in[6];
    const float* lin_b = (const float*)d_in[7];
    const float* Wfc   = (const float*)d_in[8];
    const float* bfc   = (const float*)d_in[9];
    const float* gfc   = (const float*)d_in[10];
    const float* befc  = (const float*)d_in[11];

    // ws layout (f32 units): [qkvh: TOT/2][stats: 4096][ocat: CHUNK*BB*HEADS*NN*8]
    // Y (TOT) lives inside the ocat region (dead before attn writes ocat).
    float* ws    = (float*)d_ws;
    _Float16* qkvh = (_Float16*)ws;
    float* st    = ws + (size_t)TOT/2;
    float* ocat  = st + 4096;
    float* Y     = ocat;
    float* Xo    = (float*)d_out;          // Xo lives in d_out; fc runs in place

    float* qsum   = st;            // 768
    float* qsumsq = st + 768;      // 768
    float* fsum   = st + 1536;     // 64
    float* fsumsq = st + 1600;     // 64  -> first 1664 floats zeroed each call
    float* qsc    = st + 1664;     // 768
    float* qsh    = st + 2432;     // 768
    float* fsc    = st + 3200;     // 64
    float* fsh    = st + 3264;     // 64

    hipMemsetAsync(st, 0, 1664 * sizeof(float), stream);

    qkv_gemm<<<dim3(BN/16, TS), 256, 0, stream>>>(X, STE, Wqkv, bqkv, Y);
    col_reduce<<<dim3(8, TS), 256, 0, stream>>>(Y, qsum, qsumsq, BN, BN/8);
    qkv_stats<<<3, 256, 0, stream>>>(qsum, qsumsq, gqkv, beqkv, qsc, qsh);
    bn_relayout_h<<<TOT/256, 256, 0, stream>>>(Y, qsc, qsh, qkvh);

    for (int ch = 0; ch < 3; ++ch) {
        int p0 = ch * CHUNK, p1 = p0 + CHUNK;
        attn_ocat<<<dim3(CHUNK, BB, HEADS), 256, 0, stream>>>(qkvh, ocat, p0);
        lin_chunk<<<dim3(BN/16, TS), 256, 0, stream>>>(ocat, lin_w, lin_b, Xo, p0, p1);
    }

    fc_gemm<<<ROWS_FC/16, 256, 0, stream>>>(Xo, Wfc, bfc, (float*)d_out);
    col_reduce<<<dim3(96, 1), 256, 0, stream>>>((float*)d_out, fsum, fsumsq, ROWS_FC, ROWS_FC/96);
    fc_stats<<<1, 64, 0, stream>>>(fsum, fsumsq, gfc, befc, fsc, fsh);
    bn_out<<<TOT/256, 256, 0, stream>>>((float*)d_out, fsc, fsh);
}

// Round 9
// 906.652 us; speedup vs baseline: 2.7106x; 2.5691x over previous
//
#include <hip/hip_runtime.h>
#include <math.h>

#define TS 12
#define HEADS 8
#define DH 8
#define DD 64
#define BB 16
#define NN 325
#define BN (BB*NN)               // 5200
#define TOT (TS*BN*DD)           // 3,993,600
#define ROWS_FC (BB*TS*NN)       // 62,400
#define NPAD 336                 // 21 tiles of 16
#define NT 21
#define CHUNK 26                 // pairs per chunk (78 = 3*26)
constexpr float EPS_ = 1e-5f;
constexpr float SCALE_ = 0.35355339059327373f; // 1/sqrt(8)

typedef _Float16 f16x4 __attribute__((ext_vector_type(4)));
typedef float    f32x4 __attribute__((ext_vector_type(4)));

// ---------------- K1: QKV GEMM (16 rows/block) ----------------
__global__ __launch_bounds__(256) void qkv_gemm(
    const float* __restrict__ X, const float* __restrict__ STE,
    const float* __restrict__ Wqkv, const float* __restrict__ bqkv,
    float* __restrict__ Y)
{
    __shared__ float Wl[128*64];
    int t = blockIdx.y;
    int tid = threadIdx.x;
    for (int i = tid; i < 2048; i += 256)
        ((float4*)Wl)[i] = ((const float4*)Wqkv)[i];
    __syncthreads();
    int c = tid & 63, rl = tid >> 6;
    #pragma unroll
    for (int rr = 0; rr < 4; ++rr) {
        int r = blockIdx.x * 16 + rr * 4 + rl;
        int b = r / NN, n = r % NN;
        const float4* xr = (const float4*)(X   + (((size_t)b*TS + t)*NN + n)*DD);
        const float4* sr = (const float4*)(STE + (((size_t)b*TS + t)*NN + n)*DD);
        float acc = bqkv[c];
        #pragma unroll
        for (int k4 = 0; k4 < 16; ++k4) {
            float4 xv = xr[k4];
            acc += xv.x*Wl[(4*k4+0)*64+c] + xv.y*Wl[(4*k4+1)*64+c]
                 + xv.z*Wl[(4*k4+2)*64+c] + xv.w*Wl[(4*k4+3)*64+c];
        }
        #pragma unroll
        for (int k4 = 0; k4 < 16; ++k4) {
            float4 sv = sr[k4];
            acc += sv.x*Wl[(64+4*k4+0)*64+c] + sv.y*Wl[(64+4*k4+1)*64+c]
                 + sv.z*Wl[(64+4*k4+2)*64+c] + sv.w*Wl[(64+4*k4+3)*64+c];
        }
        Y[((size_t)t*BN + r)*64 + c] = acc;
    }
}

// ---------------- K2: column reduce (sum, sumsq) over [t][R][64] ----------------
__global__ __launch_bounds__(256) void col_reduce(
    const float* __restrict__ src, float* __restrict__ osum, float* __restrict__ osumsq,
    int R, int chunkrows)
{
    __shared__ float red[256];
    int t = blockIdx.y;
    int tid = threadIdx.x;
    int c = tid & 63, rl = tid >> 6;
    int r0 = blockIdx.x * chunkrows;
    int r1 = r0 + chunkrows;
    float s = 0.f, s2 = 0.f;
    for (int r = r0 + rl; r < r1; r += 4) {
        float v = src[((size_t)t*R + r)*64 + c];
        s += v; s2 += v*v;
    }
    red[tid] = s; __syncthreads();
    if (tid < 64) atomicAdd(&osum[t*64 + tid], red[tid] + red[tid+64] + red[tid+128] + red[tid+192]);
    __syncthreads();
    red[tid] = s2; __syncthreads();
    if (tid < 64) atomicAdd(&osumsq[t*64 + tid], red[tid] + red[tid+64] + red[tid+128] + red[tid+192]);
}

// ---------------- K3: finalize QKV BN stats ----------------
__global__ void qkv_stats(const float* __restrict__ qsum, const float* __restrict__ qsumsq,
                          const float* __restrict__ g, const float* __restrict__ be,
                          float* __restrict__ qsc, float* __restrict__ qsh)
{
    int i = blockIdx.x * blockDim.x + threadIdx.x;
    if (i >= TS*64) return;
    int c = i & 63;
    float mean = qsum[i] * (1.0f / BN);
    float var  = qsumsq[i] * (1.0f / BN) - mean*mean;
    float sc = g[c] * rsqrtf(var + EPS_);
    qsc[i] = sc;
    qsh[i] = be[c] - mean * sc;
}

// ---------------- K4: BN+ReLU + relayout to f16 [t][b][h][n][8] ----------------
__global__ __launch_bounds__(256) void bn_relayout_h(
    const float* __restrict__ Y, const float* __restrict__ qsc, const float* __restrict__ qsh,
    _Float16* __restrict__ qkvh)
{
    size_t idx = (size_t)blockIdx.x * 256 + threadIdx.x;
    if (idx >= TOT) return;
    int c = (int)(idx & 63);
    size_t tr = idx >> 6;
    int t = (int)(tr / BN);
    int r = (int)(tr % BN);
    float v = fmaxf(Y[idx] * qsc[t*64 + c] + qsh[t*64 + c], 0.0f);
    int b = r / NN, n = r % NN, h = c >> 3, d = c & 7;
    qkvh[((((size_t)t*BB + b)*HEADS + h)*NN + n)*DH + d] = (_Float16)v;
}

// ---------------- K5: MFMA attention, block-exclusive contiguous ocat ----------------
// Block = (pl, b, h), pair p = p0+pl. S^T = K·Q^T via mfma_f32_16x16x16_f16;
// C-frag == B-frag layout for O^T = V^T·P^T (zero cross-lane movement).
// Two-pass softmax keeps P in [0,1] for f16.
// LAUNCH-BOUNDS FIX vs R6-R8: (256,8) capped the unified RF at 64 regs/lane;
// compiler spilled the inner-loop state to scratch -> 2.6 GB/dispatch of HBM
// traffic (the observed FETCH 1.05 GB + WRITE 1.5 GB at VGPR_Count=32).
// (256,2) lifts the cap; occupancy stays 8 blocks/CU via the 2048-thread cap.
__global__ __launch_bounds__(256, 2) void attn_ocat(
    const _Float16* __restrict__ qkvh, float* __restrict__ ocat, int p0)
{
    int pl = blockIdx.x, b = blockIdx.y, h = blockIdx.z;
    int p = p0 + pl;
    int s = 0, base = 0;
    while (base + s + 1 <= p) { base += s + 1; ++s; }
    int j = p - base;

    __shared__ _Float16 Kl[NPAD*8];          // [m][k], rows m>=325 zero
    __shared__ _Float16 VT[16][NPAD+8];      // [d][m], d>=8 & m>=325 zero

    int tid  = threadIdx.x;
    int lane = tid & 63, wv = tid >> 6;
    int lq = lane >> 4, lr = lane & 15;

    for (int i = tid; i < (NPAD*8)/2; i += 256) ((unsigned*)Kl)[i] = 0u;
    for (int i = tid; i < (16*(NPAD+8))/2; i += 256) ((unsigned*)(&VT[0][0]))[i] = 0u;
    __syncthreads();
    const _Float16* kvsrc = qkvh + (((size_t)j*BB + b)*HEADS + h)*(NN*DH);
    for (int i = tid; i < (NN*DH)/2; i += 256) ((unsigned*)Kl)[i] = ((const unsigned*)kvsrc)[i];
    for (int i = tid; i < NN*DH; i += 256) { int m = i >> 3, d = i & 7; VT[d][m] = kvsrc[i]; }
    __syncthreads();

    const _Float16* qh = qkvh + (((size_t)s*BB + b)*HEADS + h)*(NN*DH);
    float* obase = ocat + (((size_t)(pl*BB + b)*HEADS + h)*NN)*8;

    for (int st = wv; st < NT; st += 4) {
        int n0 = st * 16;
        f16x4 qf = {0,0,0,0};
        int nq = n0 + lr;
        if (lq < 2 && nq < NN) qf = *(const f16x4*)(qh + nq*DH + lq*4);
        qf *= (_Float16)SCALE_;

        // pass 1: row max (pad rows give 0; true max >= 0 since Q,K >= 0)
        float mx = 0.f;
        for (int mt = 0; mt < NT; ++mt) {
            f16x4 kf = {0,0,0,0};
            if (lq < 2) kf = *(const f16x4*)(&Kl[(mt*16 + lr)*8 + lq*4]);
            f32x4 sA = __builtin_amdgcn_mfma_f32_16x16x16f16(kf, qf, (f32x4){0.f,0.f,0.f,0.f}, 0, 0, 0);
            mx = fmaxf(mx, fmaxf(fmaxf(sA[0], sA[1]), fmaxf(sA[2], sA[3])));
        }
        mx = fmaxf(mx, __shfl_xor(mx, 16));
        mx = fmaxf(mx, __shfl_xor(mx, 32));

        // pass 2: exp(S-mx), den, O^T = V^T · P^T
        f32x4 ot = {0.f, 0.f, 0.f, 0.f};
        float den = 0.f;
        for (int mt = 0; mt < NT; ++mt) {
            f16x4 kf = {0,0,0,0};
            if (lq < 2) kf = *(const f16x4*)(&Kl[(mt*16 + lr)*8 + lq*4]);
            f32x4 sA = __builtin_amdgcn_mfma_f32_16x16x16f16(kf, qf, (f32x4){0.f,0.f,0.f,0.f}, 0, 0, 0);
            f16x4 pf;
            #pragma unroll
            for (int r = 0; r < 4; ++r) {
                float e = __expf(sA[r] - mx);
                if (mt*16 + lq*4 + r >= NN) e = 0.f;   // mask pad rows
                den += e;
                pf[r] = (_Float16)e;
            }
            f16x4 vf = *(const f16x4*)(&VT[lr][mt*16 + lq*4]);
            ot = __builtin_amdgcn_mfma_f32_16x16x16f16(vf, pf, ot, 0, 0, 0);
        }
        den += __shfl_xor(den, 16);
        den += __shfl_xor(den, 32);
        float inv = 1.0f / den;

        // store O strip contiguously: lane (lq<2, lr) -> obase[nq*8 + lq*4]
        if (lq < 2 && nq < NN) {
            float4 o4 = make_float4(ot[0]*inv, ot[1]*inv, ot[2]*inv, ot[3]*inv);
            *(float4*)(obase + (size_t)nq*8 + lq*4) = o4;
        }
    }
}

// ---------------- K6: per-step linear over concat chunk, accumulate into Xo ----------------
// Block = (rowtile, s). ocat layout [pl][b][h][n][8]. Seed with lin_b iff this
// chunk contains j=0 for step s (p0 <= base); later chunks RMW Xo.
__global__ __launch_bounds__(256) void lin_chunk(
    const float* __restrict__ ocat, const float* __restrict__ lin_w,
    const float* __restrict__ lin_b, float* Xo, int p0, int p1)
{
    int s = blockIdx.y;
    int base = s*(s+1)/2;
    int j0 = p0 - base; if (j0 < 0) j0 = 0;
    int j1 = s + 1; if (j1 > p1 - base) j1 = p1 - base;
    if (j1 <= j0) return;
    bool seed = (p0 <= base);   // first chunk containing this step's j=0

    __shared__ float Wl[64*64];
    int tid = threadIdx.x;
    int c = tid & 63, rl = tid >> 6;

    float acc[4];
    size_t xoff[4];
    int bb[4], nn_[4];
    #pragma unroll
    for (int rr = 0; rr < 4; ++rr) {
        int r = blockIdx.x*16 + rr*4 + rl;
        int b = r / NN, n = r % NN;
        bb[rr] = b; nn_[rr] = n;
        xoff[rr] = (((size_t)b*TS + s)*NN + n)*64 + c;
        acc[rr] = seed ? lin_b[s*64 + c] : Xo[xoff[rr]];
    }

    for (int jj = j0; jj < j1; ++jj) {
        __syncthreads();
        const float4* wsrc = (const float4*)(lin_w + ((size_t)s*768 + jj*64)*64);
        for (int i = tid; i < 1024; i += 256) ((float4*)Wl)[i] = wsrc[i];
        __syncthreads();
        int pl = base + jj - p0;
        #pragma unroll
        for (int rr = 0; rr < 4; ++rr) {
            const float* op0 = ocat + (((size_t)(pl*BB + bb[rr])*HEADS)*NN + nn_[rr])*8;
            #pragma unroll
            for (int h = 0; h < 8; ++h) {
                const float4* op = (const float4*)(op0 + (size_t)h*NN*8);
                float4 oa = op[0], ob = op[1];
                acc[rr] += oa.x*Wl[(h*8+0)*64+c] + oa.y*Wl[(h*8+1)*64+c]
                         + oa.z*Wl[(h*8+2)*64+c] + oa.w*Wl[(h*8+3)*64+c]
                         + ob.x*Wl[(h*8+4)*64+c] + ob.y*Wl[(h*8+5)*64+c]
                         + ob.z*Wl[(h*8+6)*64+c] + ob.w*Wl[(h*8+7)*64+c];
            }
        }
    }
    #pragma unroll
    for (int rr = 0; rr < 4; ++rr) Xo[xoff[rr]] = acc[rr];
}

// ---------------- K7: fc GEMM, IN PLACE on d_out (row-local, race-free) ----------------
__global__ __launch_bounds__(256) void fc_gemm(
    const float* Xo, const float* __restrict__ Wfc, const float* __restrict__ bfc,
    float* Yout)
{
    __shared__ float Wl[64*64];
    int tid = threadIdx.x;
    for (int i = tid; i < 1024; i += 256)
        ((float4*)Wl)[i] = ((const float4*)Wfc)[i];
    __syncthreads();
    int c = tid & 63, rl = tid >> 6;
    #pragma unroll
    for (int rr = 0; rr < 4; ++rr) {
        size_t r = (size_t)blockIdx.x * 16 + rr * 4 + rl;
        const float4* xr = (const float4*)(Xo + r * 64);
        float acc = bfc[c];
        #pragma unroll
        for (int k4 = 0; k4 < 16; ++k4) {
            float4 xv = xr[k4];
            acc += xv.x*Wl[(4*k4+0)*64+c] + xv.y*Wl[(4*k4+1)*64+c]
                 + xv.z*Wl[(4*k4+2)*64+c] + xv.w*Wl[(4*k4+3)*64+c];
        }
        Yout[r*64 + c] = acc;
    }
}

// ---------------- K8: finalize fc BN stats ----------------
__global__ void fc_stats(const float* __restrict__ fsum, const float* __restrict__ fsumsq,
                         const float* __restrict__ g, const float* __restrict__ be,
                         float* __restrict__ fsc, float* __restrict__ fsh)
{
    int c = threadIdx.x;
    if (c >= 64) return;
    float mean = fsum[c] * (1.0f / ROWS_FC);
    float var  = fsumsq[c] * (1.0f / ROWS_FC) - mean*mean;
    float sc = g[c] * rsqrtf(var + EPS_);
    fsc[c] = sc;
    fsh[c] = be[c] - mean * sc;
}

// ---------------- K9: final BN+ReLU in place on d_out ----------------
__global__ __launch_bounds__(256) void bn_out(
    float* __restrict__ out, const float* __restrict__ fsc, const float* __restrict__ fsh)
{
    size_t idx = (size_t)blockIdx.x * 256 + threadIdx.x;
    if (idx >= TOT) return;
    int c = (int)(idx & 63);
    out[idx] = fmaxf(out[idx] * fsc[c] + fsh[c], 0.0f);
}

extern "C" void kernel_launch(void* const* d_in, const int* in_sizes, int n_in,
                              void* d_out, int out_size, void* d_ws, size_t ws_size,
                              hipStream_t stream)
{
    const float* X     = (const float*)d_in[0];
    const float* STE   = (const float*)d_in[1];
    const float* Wqkv  = (const float*)d_in[2];
    const float* bqkv  = (const float*)d_in[3];
    const float* gqkv  = (const float*)d_in[4];
    const float* beqkv = (const float*)d_in[5];
    const float* lin_w = (const float*)d_in[6];
    const float* lin_b = (const float*)d_in[7];
    const float* Wfc   = (const float*)d_in[8];
    const float* bfc   = (const float*)d_in[9];
    const float* gfc   = (const float*)d_in[10];
    const float* befc  = (const float*)d_in[11];

    // ws layout (f32 units): [qkvh: TOT/2][stats: 4096][ocat: CHUNK*BB*HEADS*NN*8]
    // Y (TOT) lives inside the ocat region (dead before attn writes ocat).
    float* ws    = (float*)d_ws;
    _Float16* qkvh = (_Float16*)ws;
    float* st    = ws + (size_t)TOT/2;
    float* ocat  = st + 4096;
    float* Y     = ocat;
    float* Xo    = (float*)d_out;          // Xo lives in d_out; fc runs in place

    float* qsum   = st;            // 768
    float* qsumsq = st + 768;      // 768
    float* fsum   = st + 1536;     // 64
    float* fsumsq = st + 1600;     // 64  -> first 1664 floats zeroed each call
    float* qsc    = st + 1664;     // 768
    float* qsh    = st + 2432;     // 768
    float* fsc    = st + 3200;     // 64
    float* fsh    = st + 3264;     // 64

    hipMemsetAsync(st, 0, 1664 * sizeof(float), stream);

    qkv_gemm<<<dim3(BN/16, TS), 256, 0, stream>>>(X, STE, Wqkv, bqkv, Y);
    col_reduce<<<dim3(8, TS), 256, 0, stream>>>(Y, qsum, qsumsq, BN, BN/8);
    qkv_stats<<<3, 256, 0, stream>>>(qsum, qsumsq, gqkv, beqkv, qsc, qsh);
    bn_relayout_h<<<TOT/256, 256, 0, stream>>>(Y, qsc, qsh, qkvh);

    for (int ch = 0; ch < 3; ++ch) {
        int p0 = ch * CHUNK, p1 = p0 + CHUNK;
        attn_ocat<<<dim3(CHUNK, BB, HEADS), 256, 0, stream>>>(qkvh, ocat, p0);
        lin_chunk<<<dim3(BN/16, TS), 256, 0, stream>>>(ocat, lin_w, lin_b, Xo, p0, p1);
    }

    fc_gemm<<<ROWS_FC/16, 256, 0, stream>>>(Xo, Wfc, bfc, (float*)d_out);
    col_reduce<<<dim3(96, 1), 256, 0, stream>>>((float*)d_out, fsum, fsumsq, ROWS_FC, ROWS_FC/96);
    fc_stats<<<1, 64, 0, stream>>>(fsum, fsumsq, gfc, befc, fsc, fsh);
    bn_out<<<TOT/256, 256, 0, stream>>>((float*)d_out, fsc, fsh);
}

// Round 11
// 731.669 us; speedup vs baseline: 3.3589x; 1.2392x over previous
//
#include <hip/hip_runtime.h>
#include <math.h>

#define TS 12
#define HEADS 8
#define DH 8
#define DD 64
#define BB 16
#define NN 325
#define BN (BB*NN)               // 5200
#define TOT (TS*BN*DD)           // 3,993,600
#define ROWS_FC (BB*TS*NN)       // 62,400
#define NPAD 336                 // 21 tiles of 16
#define NT 21
#define CHUNK 26                 // pairs per chunk (78 = 3*26)
#define QROWS 80                 // rows per qkv_gemm block (5200 = 65*80)
constexpr float EPS_ = 1e-5f;
constexpr float SCALE_ = 0.35355339059327373f;   // 1/sqrt(8)
constexpr float LOG2E_ = 1.4426950408889634f;

typedef _Float16 f16x4 __attribute__((ext_vector_type(4)));
typedef _Float16 f16x2 __attribute__((ext_vector_type(2)));
typedef float    f32x4 __attribute__((ext_vector_type(4)));

// ---------------- K1: QKV GEMM (80 rows/block, LDS-staged X, 5x4 reg tile) ----------------
// R9 showed 135us at VALUBusy 13.5%: per-lane redundant broadcast global loads
// + serial acc chain = latency-bound. Now: coalesced X/STE->LDS staging, each
// thread 5 rows x 4 cols from LDS (broadcast X, float4 W), 4 indep chains/row.
__global__ __launch_bounds__(256, 2) void qkv_gemm(
    const float* __restrict__ X, const float* __restrict__ STE,
    const float* __restrict__ Wqkv, const float* __restrict__ bqkv,
    float* __restrict__ Y)
{
    __shared__ float Wl[128*64];        // 32 KB
    __shared__ float Xl[QROWS][132];    // 41.25 KB (pad 128->132)
    int t = blockIdx.y;
    int tid = threadIdx.x;
    int r0 = blockIdx.x * QROWS;
    for (int i = tid; i < 2048; i += 256)
        ((float4*)Wl)[i] = ((const float4*)Wqkv)[i];
    for (int i = tid; i < QROWS*32; i += 256) {
        int row = i >> 5, q = i & 31;
        int r = r0 + row;
        int b = r / NN, n = r % NN;
        size_t src = (((size_t)b*TS + t)*NN + n)*DD;
        float4 v = (q < 16) ? ((const float4*)(X + src))[q]
                            : ((const float4*)(STE + src))[q-16];
        *(float4*)&Xl[row][q*4] = v;
    }
    __syncthreads();
    int cg = tid & 15, rg = tid >> 4;
    int c0 = cg*4;
    float4 a[5] = {};
    #pragma unroll 4
    for (int k4 = 0; k4 < 32; ++k4) {
        float4 w0 = *(const float4*)&Wl[(4*k4+0)*64 + c0];
        float4 w1 = *(const float4*)&Wl[(4*k4+1)*64 + c0];
        float4 w2 = *(const float4*)&Wl[(4*k4+2)*64 + c0];
        float4 w3 = *(const float4*)&Wl[(4*k4+3)*64 + c0];
        #pragma unroll
        for (int i = 0; i < 5; ++i) {
            float4 xv = *(const float4*)&Xl[rg*5 + i][k4*4];
            a[i].x += xv.x*w0.x + xv.y*w1.x + xv.z*w2.x + xv.w*w3.x;
            a[i].y += xv.x*w0.y + xv.y*w1.y + xv.z*w2.y + xv.w*w3.y;
            a[i].z += xv.x*w0.z + xv.y*w1.z + xv.z*w2.z + xv.w*w3.z;
            a[i].w += xv.x*w0.w + xv.y*w1.w + xv.z*w2.w + xv.w*w3.w;
        }
    }
    float4 bq = *(const float4*)(bqkv + c0);
    #pragma unroll
    for (int i = 0; i < 5; ++i) {
        int r = r0 + rg*5 + i;
        float4 o;
        o.x = a[i].x + bq.x; o.y = a[i].y + bq.y;
        o.z = a[i].z + bq.z; o.w = a[i].w + bq.w;
        *(float4*)&Y[((size_t)t*BN + r)*64 + c0] = o;
    }
}

// ---------------- K2: column reduce (sum, sumsq) over [t][R][64] ----------------
__global__ __launch_bounds__(256) void col_reduce(
    const float* __restrict__ src, float* __restrict__ osum, float* __restrict__ osumsq,
    int R, int chunkrows)
{
    __shared__ float red[256];
    int t = blockIdx.y;
    int tid = threadIdx.x;
    int c = tid & 63, rl = tid >> 6;
    int r0 = blockIdx.x * chunkrows;
    int r1 = r0 + chunkrows;
    float s = 0.f, s2 = 0.f;
    for (int r = r0 + rl; r < r1; r += 4) {
        float v = src[((size_t)t*R + r)*64 + c];
        s += v; s2 += v*v;
    }
    red[tid] = s; __syncthreads();
    if (tid < 64) atomicAdd(&osum[t*64 + tid], red[tid] + red[tid+64] + red[tid+128] + red[tid+192]);
    __syncthreads();
    red[tid] = s2; __syncthreads();
    if (tid < 64) atomicAdd(&osumsq[t*64 + tid], red[tid] + red[tid+64] + red[tid+128] + red[tid+192]);
}

// ---------------- K3: finalize QKV BN stats ----------------
__global__ void qkv_stats(const float* __restrict__ qsum, const float* __restrict__ qsumsq,
                          const float* __restrict__ g, const float* __restrict__ be,
                          float* __restrict__ qsc, float* __restrict__ qsh)
{
    int i = blockIdx.x * blockDim.x + threadIdx.x;
    if (i >= TS*64) return;
    int c = i & 63;
    float mean = qsum[i] * (1.0f / BN);
    float var  = qsumsq[i] * (1.0f / BN) - mean*mean;
    float sc = g[c] * rsqrtf(var + EPS_);
    qsc[i] = sc;
    qsh[i] = be[c] - mean * sc;
}

// ---------------- K4: BN+ReLU + relayout to f16 [t][b][h][n][8] ----------------
__global__ __launch_bounds__(256) void bn_relayout_h(
    const float* __restrict__ Y, const float* __restrict__ qsc, const float* __restrict__ qsh,
    _Float16* __restrict__ qkvh)
{
    size_t idx = (size_t)blockIdx.x * 256 + threadIdx.x;
    if (idx >= TOT) return;
    int c = (int)(idx & 63);
    size_t tr = idx >> 6;
    int t = (int)(tr / BN);
    int r = (int)(tr % BN);
    float v = fmaxf(Y[idx] * qsc[t*64 + c] + qsh[t*64 + c], 0.0f);
    int b = r / NN, n = r % NN, h = c >> 3, d = c & 7;
    qkvh[((((size_t)t*BB + b)*HEADS + h)*NN + n)*DH + d] = (_Float16)v;
}

// ---------------- K5: MFMA attention, registerized S, free den ----------------
// Block = (pl, b, h). S^T = K.Q^T via mfma_f32_16x16x16_f16; S tiles kept in
// registers across the softmax (full unroll -> static indexing, no scratch).
// Q pre-scaled by SCALE*log2e so exp = single v_exp_f32 (2^x native).
// V^T row 8 = ones -> PV MFMA's C-row 8 computes den for free.
// Pad-row masking only on the last tile (mt=20).
__global__ __launch_bounds__(256, 2) void attn_ocat(
    const _Float16* __restrict__ qkvh, float* __restrict__ ocat, int p0)
{
    int pl = blockIdx.x, b = blockIdx.y, h = blockIdx.z;
    int p = p0 + pl;
    int s = 0, base = 0;
    while (base + s + 1 <= p) { base += s + 1; ++s; }
    int j = p - base;

    __shared__ _Float16 Kl[NPAD*8];          // [m][k], rows m>=325 zero
    __shared__ _Float16 VT[16][NPAD+8];      // [d][m], d 9..15 zero, d=8 ones

    int tid  = threadIdx.x;
    int lane = tid & 63, wv = tid >> 6;
    int lq = lane >> 4, lr = lane & 15;

    for (int i = tid; i < (NPAD*8)/2; i += 256) ((unsigned*)Kl)[i] = 0u;
    for (int i = tid; i < (16*(NPAD+8))/2; i += 256) ((unsigned*)(&VT[0][0]))[i] = 0u;
    __syncthreads();
    const _Float16* kvsrc = qkvh + (((size_t)j*BB + b)*HEADS + h)*(NN*DH);
    for (int i = tid; i < (NN*DH)/2; i += 256) ((unsigned*)Kl)[i] = ((const unsigned*)kvsrc)[i];
    for (int i = tid; i < NN*DH; i += 256) { int m = i >> 3, d = i & 7; VT[d][m] = kvsrc[i]; }
    for (int i = tid; i < NPAD; i += 256) VT[8][i] = (_Float16)1.0f;   // den row
    __syncthreads();

    const _Float16* qh = qkvh + (((size_t)s*BB + b)*HEADS + h)*(NN*DH);
    float* obase = ocat + (((size_t)(pl*BB + b)*HEADS + h)*NN)*8;

    for (int st = wv; st < NT; st += 4) {
        int n0 = st * 16;
        f16x4 qf = {0,0,0,0};
        int nq = n0 + lr;
        if (lq < 2 && nq < NN) qf = *(const f16x4*)(qh + nq*DH + lq*4);
        qf *= (_Float16)(SCALE_ * LOG2E_);   // log2-domain scores

        // pass 1: QK^T MFMAs, S kept in registers; row max
        f32x4 S[NT];
        float mx = 0.f;
        #pragma unroll
        for (int mt = 0; mt < NT; ++mt) {
            f16x4 kf = {0,0,0,0};
            if (lq < 2) kf = *(const f16x4*)(&Kl[(mt*16 + lr)*8 + lq*4]);
            S[mt] = __builtin_amdgcn_mfma_f32_16x16x16f16(kf, qf, (f32x4){0.f,0.f,0.f,0.f}, 0, 0, 0);
            mx = fmaxf(mx, fmaxf(fmaxf(S[mt][0], S[mt][1]), fmaxf(S[mt][2], S[mt][3])));
        }
        mx = fmaxf(mx, __shfl_xor(mx, 16));
        mx = fmaxf(mx, __shfl_xor(mx, 32));

        // pass 2: P = 2^(S-mx) from registers, O^T = V^T.P^T (row 8 -> den)
        f32x4 ot = {0.f, 0.f, 0.f, 0.f};
        #pragma unroll
        for (int mt = 0; mt < NT; ++mt) {
            float e0 = __builtin_amdgcn_exp2f(S[mt][0] - mx);
            float e1 = __builtin_amdgcn_exp2f(S[mt][1] - mx);
            float e2 = __builtin_amdgcn_exp2f(S[mt][2] - mx);
            float e3 = __builtin_amdgcn_exp2f(S[mt][3] - mx);
            if (mt == NT-1) {                 // only tile 20 has pad rows (m>=325)
                if (lq*4 + 0 >= 5) e0 = 0.f;
                if (lq*4 + 1 >= 5) e1 = 0.f;
                if (lq*4 + 2 >= 5) e2 = 0.f;
                if (lq*4 + 3 >= 5) e3 = 0.f;
            }
            // cvt_pkrtz returns __fp16x2; bit-identical to f16x2 -> bit_cast
            f16x2 plo = __builtin_bit_cast(f16x2, __builtin_amdgcn_cvt_pkrtz(e0, e1));
            f16x2 phi = __builtin_bit_cast(f16x2, __builtin_amdgcn_cvt_pkrtz(e2, e3));
            f16x4 pf = {plo.x, plo.y, phi.x, phi.y};
            f16x4 vf = *(const f16x4*)(&VT[lr][mt*16 + lq*4]);
            ot = __builtin_amdgcn_mfma_f32_16x16x16f16(vf, pf, ot, 0, 0, 0);
        }
        float den = __shfl(ot[0], 32 + lr);   // C row 8 lives in lanes 32..47
        float inv = __builtin_amdgcn_rcpf(den);

        if (lq < 2 && nq < NN) {
            float4 o4 = make_float4(ot[0]*inv, ot[1]*inv, ot[2]*inv, ot[3]*inv);
            *(float4*)(obase + (size_t)nq*8 + lq*4) = o4;
        }
    }
}

// ---------------- K6: per-step linear over concat chunk, accumulate into Xo ----------------
__global__ __launch_bounds__(256) void lin_chunk(
    const float* __restrict__ ocat, const float* __restrict__ lin_w,
    const float* __restrict__ lin_b, float* Xo, int p0, int p1)
{
    int s = blockIdx.y;
    int base = s*(s+1)/2;
    int j0 = p0 - base; if (j0 < 0) j0 = 0;
    int j1 = s + 1; if (j1 > p1 - base) j1 = p1 - base;
    if (j1 <= j0) return;
    bool seed = (p0 <= base);   // first chunk containing this step's j=0

    __shared__ float Wl[64*64];
    int tid = threadIdx.x;
    int c = tid & 63, rl = tid >> 6;

    float acc[4];
    size_t xoff[4];
    int bb[4], nn_[4];
    #pragma unroll
    for (int rr = 0; rr < 4; ++rr) {
        int r = blockIdx.x*16 + rr*4 + rl;
        int b = r / NN, n = r % NN;
        bb[rr] = b; nn_[rr] = n;
        xoff[rr] = (((size_t)b*TS + s)*NN + n)*64 + c;
        acc[rr] = seed ? lin_b[s*64 + c] : Xo[xoff[rr]];
    }

    for (int jj = j0; jj < j1; ++jj) {
        __syncthreads();
        const float4* wsrc = (const float4*)(lin_w + ((size_t)s*768 + jj*64)*64);
        for (int i = tid; i < 1024; i += 256) ((float4*)Wl)[i] = wsrc[i];
        __syncthreads();
        int pl = base + jj - p0;
        #pragma unroll
        for (int rr = 0; rr < 4; ++rr) {
            const float* op0 = ocat + (((size_t)(pl*BB + bb[rr])*HEADS)*NN + nn_[rr])*8;
            #pragma unroll
            for (int h = 0; h < 8; ++h) {
                const float4* op = (const float4*)(op0 + (size_t)h*NN*8);
                float4 oa = op[0], ob = op[1];
                acc[rr] += oa.x*Wl[(h*8+0)*64+c] + oa.y*Wl[(h*8+1)*64+c]
                         + oa.z*Wl[(h*8+2)*64+c] + oa.w*Wl[(h*8+3)*64+c]
                         + ob.x*Wl[(h*8+4)*64+c] + ob.y*Wl[(h*8+5)*64+c]
                         + ob.z*Wl[(h*8+6)*64+c] + ob.w*Wl[(h*8+7)*64+c];
            }
        }
    }
    #pragma unroll
    for (int rr = 0; rr < 4; ++rr) Xo[xoff[rr]] = acc[rr];
}

// ---------------- K7: fc GEMM, IN PLACE on d_out (row-local, race-free) ----------------
__global__ __launch_bounds__(256) void fc_gemm(
    const float* Xo, const float* __restrict__ Wfc, const float* __restrict__ bfc,
    float* Yout)
{
    __shared__ float Wl[64*64];
    int tid = threadIdx.x;
    for (int i = tid; i < 1024; i += 256)
        ((float4*)Wl)[i] = ((const float4*)Wfc)[i];
    __syncthreads();
    int c = tid & 63, rl = tid >> 6;
    #pragma unroll
    for (int rr = 0; rr < 4; ++rr) {
        size_t r = (size_t)blockIdx.x * 16 + rr * 4 + rl;
        const float4* xr = (const float4*)(Xo + r * 64);
        float acc = bfc[c];
        #pragma unroll
        for (int k4 = 0; k4 < 16; ++k4) {
            float4 xv = xr[k4];
            acc += xv.x*Wl[(4*k4+0)*64+c] + xv.y*Wl[(4*k4+1)*64+c]
                 + xv.z*Wl[(4*k4+2)*64+c] + xv.w*Wl[(4*k4+3)*64+c];
        }
        Yout[r*64 + c] = acc;
    }
}

// ---------------- K8: finalize fc BN stats ----------------
__global__ void fc_stats(const float* __restrict__ fsum, const float* __restrict__ fsumsq,
                         const float* __restrict__ g, const float* __restrict__ be,
                         float* __restrict__ fsc, float* __restrict__ fsh)
{
    int c = threadIdx.x;
    if (c >= 64) return;
    float mean = fsum[c] * (1.0f / ROWS_FC);
    float var  = fsumsq[c] * (1.0f / ROWS_FC) - mean*mean;
    float sc = g[c] * rsqrtf(var + EPS_);
    fsc[c] = sc;
    fsh[c] = be[c] - mean * sc;
}

// ---------------- K9: final BN+ReLU in place on d_out ----------------
__global__ __launch_bounds__(256) void bn_out(
    float* __restrict__ out, const float* __restrict__ fsc, const float* __restrict__ fsh)
{
    size_t idx = (size_t)blockIdx.x * 256 + threadIdx.x;
    if (idx >= TOT) return;
    int c = (int)(idx & 63);
    out[idx] = fmaxf(out[idx] * fsc[c] + fsh[c], 0.0f);
}

extern "C" void kernel_launch(void* const* d_in, const int* in_sizes, int n_in,
                              void* d_out, int out_size, void* d_ws, size_t ws_size,
                              hipStream_t stream)
{
    const float* X     = (const float*)d_in[0];
    const float* STE   = (const float*)d_in[1];
    const float* Wqkv  = (const float*)d_in[2];
    const float* bqkv  = (const float*)d_in[3];
    const float* gqkv  = (const float*)d_in[4];
    const float* beqkv = (const float*)d_in[5];
    const float* lin_w = (const float*)d_in[6];
    const float* lin_b = (const float*)d_in[7];
    const float* Wfc   = (const float*)d_in[8];
    const float* bfc   = (const float*)d_in[9];
    const float* gfc   = (const float*)d_in[10];
    const float* befc  = (const float*)d_in[11];

    // ws layout (f32 units): [qkvh: TOT/2][stats: 4096][ocat: CHUNK*BB*HEADS*NN*8]
    // Y (TOT) lives inside the ocat region (dead before attn writes ocat).
    float* ws    = (float*)d_ws;
    _Float16* qkvh = (_Float16*)ws;
    float* st    = ws + (size_t)TOT/2;
    float* ocat  = st + 4096;
    float* Y     = ocat;
    float* Xo    = (float*)d_out;          // Xo lives in d_out; fc runs in place

    float* qsum   = st;            // 768
    float* qsumsq = st + 768;      // 768
    float* fsum   = st + 1536;     // 64
    float* fsumsq = st + 1600;     // 64  -> first 1664 floats zeroed each call
    float* qsc    = st + 1664;     // 768
    float* qsh    = st + 2432;     // 768
    float* fsc    = st + 3200;     // 64
    float* fsh    = st + 3264;     // 64

    hipMemsetAsync(st, 0, 1664 * sizeof(float), stream);

    qkv_gemm<<<dim3(BN/QROWS, TS), 256, 0, stream>>>(X, STE, Wqkv, bqkv, Y);
    col_reduce<<<dim3(8, TS), 256, 0, stream>>>(Y, qsum, qsumsq, BN, BN/8);
    qkv_stats<<<3, 256, 0, stream>>>(qsum, qsumsq, gqkv, beqkv, qsc, qsh);
    bn_relayout_h<<<TOT/256, 256, 0, stream>>>(Y, qsc, qsh, qkvh);

    for (int ch = 0; ch < 3; ++ch) {
        int p0 = ch * CHUNK, p1 = p0 + CHUNK;
        attn_ocat<<<dim3(CHUNK, BB, HEADS), 256, 0, stream>>>(qkvh, ocat, p0);
        lin_chunk<<<dim3(BN/16, TS), 256, 0, stream>>>(ocat, lin_w, lin_b, Xo, p0, p1);
    }

    fc_gemm<<<ROWS_FC/16, 256, 0, stream>>>(Xo, Wfc, bfc, (float*)d_out);
    col_reduce<<<dim3(96, 1), 256, 0, stream>>>((float*)d_out, fsum, fsumsq, ROWS_FC, ROWS_FC/96);
    fc_stats<<<1, 64, 0, stream>>>(fsum, fsumsq, gfc, befc, fsc, fsh);
    bn_out<<<TOT/256, 256, 0, stream>>>((float*)d_out, fsc, fsh);
}